// Round 1
// baseline (2691.344 us; speedup 1.0000x reference)
//
#include <hip/hip_runtime.h>
#include <math.h>

#define NT 4096      // B*T
#define DD 1024      // D == DM
#define NH 16
#define HSZ 64
#define GN_EPS 1e-5f
#define DECAY_C -0.606531f

__device__ __forceinline__ float sigm(float x) { return 1.f / (1.f + __expf(-x)); }

// Generic fp32 GEMM: out[4096, Dout] = act( X @ W + bias )
// X[n,d] = Acur[n,d] + lam[d]*(Aprev[n,d]-Acur[n,d])  if lam != nullptr
//        = Acur[n,d]                                   otherwise
// act: 0 none, 1 tanh, 2 sigmoid
__global__ __launch_bounds__(256)
void gemm_mix(const float* __restrict__ Acur, const float* __restrict__ Aprev,
              const float* __restrict__ lam, const float* __restrict__ W,
              const float* __restrict__ bias, float* __restrict__ out,
              int K, int Dout, int act)
{
    __shared__ float As[64][17];
    __shared__ float Bs[16][65];
    const int tid = threadIdx.x;
    const int rowBase = blockIdx.x * 64;
    const int colBase = blockIdx.y * 64;
    const int tx = tid & 15, ty = tid >> 4;
    float acc[4][4] = {};

    for (int k0 = 0; k0 < K; k0 += 16) {
#pragma unroll
        for (int i = 0; i < 4; i++) {
            int idx = tid + i * 256;
            int r = idx >> 4, c = idx & 15;
            int grow = rowBase + r, gcol = k0 + c;
            float x = Acur[(size_t)grow * K + gcol];
            if (lam) {
                float pv = Aprev[(size_t)grow * K + gcol];
                x = x + lam[gcol] * (pv - x);
            }
            As[r][c] = x;
        }
#pragma unroll
        for (int i = 0; i < 4; i++) {
            int idx = tid + i * 256;
            int r = idx >> 6, c = idx & 63;
            int gc = colBase + c;
            Bs[r][c] = (gc < Dout) ? W[(size_t)(k0 + r) * Dout + gc] : 0.f;
        }
        __syncthreads();
#pragma unroll
        for (int kk = 0; kk < 16; kk++) {
            float av[4], bv[4];
#pragma unroll
            for (int i = 0; i < 4; i++) av[i] = As[ty * 4 + i][kk];
#pragma unroll
            for (int j = 0; j < 4; j++) bv[j] = Bs[kk][tx * 4 + j];
#pragma unroll
            for (int i = 0; i < 4; i++)
#pragma unroll
                for (int j = 0; j < 4; j++) acc[i][j] += av[i] * bv[j];
        }
        __syncthreads();
    }

#pragma unroll
    for (int i = 0; i < 4; i++) {
        int grow = rowBase + ty * 4 + i;
#pragma unroll
        for (int j = 0; j < 4; j++) {
            int gc = colBase + tx * 4 + j;
            if (gc < Dout) {
                float v = acc[i][j];
                if (bias) v += bias[gc];
                if (act == 1) v = tanhf(v);
                else if (act == 2) v = sigm(v);
                out[(size_t)grow * Dout + gc] = v;
            }
        }
    }
}

// Per-token elementwise: kk normalize per head, k scale, v lerp, wdec, rk_sum.
// In-place: k_buf (k0 -> k final), v_buf (v0 -> v final), wl_buf (wl -> wdec).
__global__ __launch_bounds__(256)
void elemwise1(const float* __restrict__ r_buf, float* __restrict__ wl_buf,
               float* __restrict__ k_buf, float* __restrict__ v_buf,
               float* __restrict__ kkn_buf, const float* __restrict__ a_buf,
               const float* __restrict__ vg_buf, const float* __restrict__ vfirst,
               const float* __restrict__ kkw, const float* __restrict__ kaw,
               const float* __restrict__ rkw, float* __restrict__ rk_sum)
{
    const int tok = blockIdx.x;
    const int tid = threadIdx.x;
    const int d0 = tid * 4;
    const size_t base = (size_t)tok * DD + d0;

    float4 k0 = *(const float4*)(k_buf + base);
    float4 a4 = *(const float4*)(a_buf + base);
    float4 wl = *(const float4*)(wl_buf + base);
    float4 v0 = *(const float4*)(v_buf + base);
    float4 vg = *(const float4*)(vg_buf + base);
    float4 vf = *(const float4*)(vfirst + base);
    float4 r4 = *(const float4*)(r_buf + base);
    float4 kkc = *(const float4*)(kkw + d0);
    float4 kac = *(const float4*)(kaw + d0);
    float4 rkc = *(const float4*)(rkw + d0);

    // kk = k0 * k_k, normalized per head (64 elems = 16 threads)
    float kk0 = k0.x * kkc.x, kk1 = k0.y * kkc.y, kk2 = k0.z * kkc.z, kk3 = k0.w * kkc.w;
    float ss = kk0 * kk0 + kk1 * kk1 + kk2 * kk2 + kk3 * kk3;
    ss += __shfl_xor(ss, 1); ss += __shfl_xor(ss, 2);
    ss += __shfl_xor(ss, 4); ss += __shfl_xor(ss, 8);
    float rn = rsqrtf(ss);
    float4 kkn = { kk0 * rn, kk1 * rn, kk2 * rn, kk3 * rn };
    *(float4*)(kkn_buf + base) = kkn;

    // k final
    float4 kf;
    kf.x = k0.x * (1.f + (a4.x - 1.f) * kac.x);
    kf.y = k0.y * (1.f + (a4.y - 1.f) * kac.y);
    kf.z = k0.z * (1.f + (a4.z - 1.f) * kac.z);
    kf.w = k0.w * (1.f + (a4.w - 1.f) * kac.w);
    *(float4*)(k_buf + base) = kf;

    // rk_sum per head
    float rk = r4.x * kf.x * rkc.x + r4.y * kf.y * rkc.y + r4.z * kf.z * rkc.z + r4.w * kf.w * rkc.w;
    rk += __shfl_xor(rk, 1); rk += __shfl_xor(rk, 2);
    rk += __shfl_xor(rk, 4); rk += __shfl_xor(rk, 8);
    if ((tid & 15) == 0) rk_sum[(size_t)tok * NH + (tid >> 4)] = rk;

    // v final
    float4 vfin;
    vfin.x = v0.x + (vf.x - v0.x) * vg.x;
    vfin.y = v0.y + (vf.y - v0.y) * vg.y;
    vfin.z = v0.z + (vf.z - v0.z) * vg.z;
    vfin.w = v0.w + (vf.w - v0.w) * vg.w;
    *(float4*)(v_buf + base) = vfin;

    // decay
    float4 wd;
    wd.x = __expf(DECAY_C * sigm(wl.x));
    wd.y = __expf(DECAY_C * sigm(wl.y));
    wd.z = __expf(DECAY_C * sigm(wl.z));
    wd.w = __expf(DECAY_C * sigm(wl.w));
    *(float4*)(wl_buf + base) = wd;
}

// Sequential scan over T. One block per (b,h); 512 threads: thread (row=tid>>3,
// q=tid&7) owns state[row][q*8 .. q*8+8) in registers. Per step: double-buffered
// LDS staging of the 6 per-step vectors, 1 barrier/step, 3-shfl row reductions.
__global__ __launch_bounds__(512)
void scan_kernel(const float* __restrict__ r_buf, const float* __restrict__ w_buf,
                 const float* __restrict__ k_buf, const float* __restrict__ kkn_buf,
                 const float* __restrict__ a_buf, const float* __restrict__ v_buf,
                 float* __restrict__ out_scan, float* __restrict__ state_out)
{
    __shared__ float buf[2][384];  // [r|w|k|kk|a|v] x 64
    const int bh = blockIdx.x;
    const int b = bh >> 4, h = bh & 15;
    const int tid = threadIdx.x;
    const int row = tid >> 3, q = tid & 7;
    float s[8] = {};
    const size_t tok0 = ((size_t)b * 1024) * DD + h * HSZ;

    const float* src = nullptr;
    int dsto = 0;
    if (tid < 96) {
        int arr = tid >> 4;
        int e = (tid & 15) * 4;
        const float* bs;
        if (arr == 0) bs = r_buf;
        else if (arr == 1) bs = w_buf;
        else if (arr == 2) bs = k_buf;
        else if (arr == 3) bs = kkn_buf;
        else if (arr == 4) bs = a_buf;
        else bs = v_buf;
        src = bs + tok0 + e;
        dsto = arr * 64 + e;
        *(float4*)&buf[0][dsto] = *(const float4*)src;
        src += DD;
    }
    __syncthreads();

    int p = 0;
    float* yout = out_scan + tok0 + row;
    for (int t = 0; t < 1024; t++) {
        float4 nv;
        const bool more = (src != nullptr) && (t < 1023);
        if (more) nv = *(const float4*)src;

        const float* bp = buf[p];
        float rr[8], ww[8], kv[8], kn[8], aa[8];
        *(float4*)&rr[0] = *(const float4*)&bp[q * 8];
        *(float4*)&rr[4] = *(const float4*)&bp[q * 8 + 4];
        *(float4*)&ww[0] = *(const float4*)&bp[64 + q * 8];
        *(float4*)&ww[4] = *(const float4*)&bp[64 + q * 8 + 4];
        *(float4*)&kv[0] = *(const float4*)&bp[128 + q * 8];
        *(float4*)&kv[4] = *(const float4*)&bp[128 + q * 8 + 4];
        *(float4*)&kn[0] = *(const float4*)&bp[192 + q * 8];
        *(float4*)&kn[4] = *(const float4*)&bp[192 + q * 8 + 4];
        *(float4*)&aa[0] = *(const float4*)&bp[256 + q * 8];
        *(float4*)&aa[4] = *(const float4*)&bp[256 + q * 8 + 4];
        float vv = bp[320 + row];

        float sa = 0.f;
#pragma unroll
        for (int j = 0; j < 8; j++) sa += s[j] * kn[j];
        sa = -sa;  // at = -kk
        sa += __shfl_xor(sa, 1); sa += __shfl_xor(sa, 2); sa += __shfl_xor(sa, 4);

        float y = 0.f;
#pragma unroll
        for (int j = 0; j < 8; j++) {
            float bt = kn[j] * aa[j];
            s[j] = s[j] * ww[j] + sa * bt + vv * kv[j];
            y += s[j] * rr[j];
        }
        y += __shfl_xor(y, 1); y += __shfl_xor(y, 2); y += __shfl_xor(y, 4);
        if (q == 0) yout[(size_t)t * DD] = y;

        if (more) {
            *(float4*)&buf[1 - p][dsto] = nv;
            src += DD;
        }
        __syncthreads();
        p ^= 1;
    }

    float* so = state_out + ((size_t)(b * NH + h) * HSZ + row) * HSZ + q * 8;
    *(float4*)so = *(float4*)&s[0];
    *(float4*)(so + 4) = *(float4*)&s[4];
}

// GroupNorm per head + rk_sum*v residual + g gate -> z
__global__ __launch_bounds__(256)
void elemwise2(const float* __restrict__ out_scan, const float* __restrict__ rk_sum,
               const float* __restrict__ v_buf, const float* __restrict__ g_buf,
               const float* __restrict__ gscale, const float* __restrict__ gbias,
               float* __restrict__ z_buf)
{
    const int tok = blockIdx.x;
    const int tid = threadIdx.x;
    const int d0 = tid * 4;
    const size_t base = (size_t)tok * DD + d0;

    float4 o = *(const float4*)(out_scan + base);
    float sm = o.x + o.y + o.z + o.w;
    float ss = o.x * o.x + o.y * o.y + o.z * o.z + o.w * o.w;
    sm += __shfl_xor(sm, 1); sm += __shfl_xor(sm, 2);
    sm += __shfl_xor(sm, 4); sm += __shfl_xor(sm, 8);
    ss += __shfl_xor(ss, 1); ss += __shfl_xor(ss, 2);
    ss += __shfl_xor(ss, 4); ss += __shfl_xor(ss, 8);
    float mu = sm * (1.f / 64.f);
    float var = ss * (1.f / 64.f) - mu * mu;
    float rs = rsqrtf(var + GN_EPS);
    float rk = rk_sum[(size_t)tok * NH + (tid >> 4)];

    float4 v4 = *(const float4*)(v_buf + base);
    float4 g4 = *(const float4*)(g_buf + base);
    float4 gs = *(const float4*)(gscale + d0);
    float4 gb = *(const float4*)(gbias + d0);
    float4 z;
    z.x = ((o.x - mu) * rs * gs.x + gb.x + rk * v4.x) * g4.x;
    z.y = ((o.y - mu) * rs * gs.y + gb.y + rk * v4.y) * g4.y;
    z.z = ((o.z - mu) * rs * gs.z + gb.z + rk * v4.z) * g4.z;
    z.w = ((o.w - mu) * rs * gs.w + gb.w + rk * v4.w) * g4.w;
    *(float4*)(z_buf + base) = z;
}

extern "C" void kernel_launch(void* const* d_in, const int* in_sizes, int n_in,
                              void* d_out, int out_size, void* d_ws, size_t ws_size,
                              hipStream_t stream) {
    const float* cur    = (const float*)d_in[0];
    const float* prev   = (const float*)d_in[1];
    const float* vfirst = (const float*)d_in[2];
    const float* rwkvag = (const float*)d_in[3];
    const float* rw_W   = (const float*)d_in[4];
    const float* w1     = (const float*)d_in[5];
    const float* w2     = (const float*)d_in[6];
    const float* w2_b   = (const float*)d_in[7];
    const float* kw_W   = (const float*)d_in[8];
    const float* vw_W   = (const float*)d_in[9];
    const float* a1     = (const float*)d_in[10];
    const float* a2     = (const float*)d_in[11];
    const float* a2_b   = (const float*)d_in[12];
    const float* v1     = (const float*)d_in[13];
    const float* v2     = (const float*)d_in[14];
    const float* v2_b   = (const float*)d_in[15];
    const float* g1     = (const float*)d_in[16];
    const float* g2     = (const float*)d_in[17];
    const float* g2_b   = (const float*)d_in[18];
    const float* k_k    = (const float*)d_in[19];
    const float* k_a    = (const float*)d_in[20];
    const float* r_k    = (const float*)d_in[21];
    const float* gn_s   = (const float*)d_in[22];
    const float* gn_b   = (const float*)d_in[23];
    const float* out_W  = (const float*)d_in[24];

    float* out = (float*)d_out;
    float* y_out = out;                                  // 4096*1024
    float* state_out = out + (size_t)NT * DD;            // 4*16*64*64
    float* vf_out = state_out + (size_t)4 * NH * HSZ * HSZ;

    // workspace layout (fp32): 8 big buffers + LoRA hiddens + rk_sum (~139 MB)
    float* ws = (float*)d_ws;
    const size_t big = (size_t)NT * DD;
    float* r_buf   = ws;
    float* w_buf   = r_buf + big;    // wl -> wdec in place
    float* k_buf   = w_buf + big;    // k0 -> k final
    float* v_buf   = k_buf + big;    // v0 -> v final
    float* kkn_buf = v_buf + big;    // kk normalized; reused as z after scan
    float* a_buf   = kkn_buf + big;
    float* g_buf   = a_buf + big;
    float* vg_buf  = g_buf + big;    // v-gate; reused as out_scan after E1
    float* os_buf  = vg_buf;
    float* hw_buf  = vg_buf + big;           // 4096*64
    float* ha_buf  = hw_buf + (size_t)NT * 64;
    float* hv_buf  = ha_buf + (size_t)NT * 64;   // 4096*32
    float* hg_buf  = hv_buf + (size_t)NT * 32;   // 4096*128
    float* rks_buf = hg_buf + (size_t)NT * 128;  // 4096*16

    dim3 blk(256);
    dim3 gBig(64, 16);
    dim3 g64t(64, 1);
    dim3 g128t(64, 2);

    // r = Xr @ rw_W
    gemm_mix<<<gBig, blk, 0, stream>>>(cur, prev, rwkvag + 0 * DD, rw_W, nullptr, r_buf, DD, DD, 0);
    // wl = tanh(Xw @ w1) @ w2 + w2_b
    gemm_mix<<<g64t, blk, 0, stream>>>(cur, prev, rwkvag + 1 * DD, w1, nullptr, hw_buf, DD, 64, 1);
    gemm_mix<<<gBig, blk, 0, stream>>>(hw_buf, nullptr, nullptr, w2, w2_b, w_buf, 64, DD, 0);
    // k0 = Xk @ kw_W ; v0 = Xv @ vw_W
    gemm_mix<<<gBig, blk, 0, stream>>>(cur, prev, rwkvag + 2 * DD, kw_W, nullptr, k_buf, DD, DD, 0);
    gemm_mix<<<gBig, blk, 0, stream>>>(cur, prev, rwkvag + 3 * DD, vw_W, nullptr, v_buf, DD, DD, 0);
    // a = sigmoid((Xa @ a1) @ a2 + a2_b)
    gemm_mix<<<g64t, blk, 0, stream>>>(cur, prev, rwkvag + 4 * DD, a1, nullptr, ha_buf, DD, 64, 0);
    gemm_mix<<<gBig, blk, 0, stream>>>(ha_buf, nullptr, nullptr, a2, a2_b, a_buf, 64, DD, 2);
    // vg = sigmoid((Xv @ v1) @ v2 + v2_b)
    gemm_mix<<<g64t, blk, 0, stream>>>(cur, prev, rwkvag + 3 * DD, v1, nullptr, hv_buf, DD, 32, 0);
    gemm_mix<<<gBig, blk, 0, stream>>>(hv_buf, nullptr, nullptr, v2, v2_b, vg_buf, 32, DD, 2);
    // g = sigmoid(Xg @ g1) @ g2 + g2_b
    gemm_mix<<<g128t, blk, 0, stream>>>(cur, prev, rwkvag + 5 * DD, g1, nullptr, hg_buf, DD, 128, 2);
    gemm_mix<<<gBig, blk, 0, stream>>>(hg_buf, nullptr, nullptr, g2, g2_b, g_buf, 128, DD, 0);

    elemwise1<<<NT, blk, 0, stream>>>(r_buf, w_buf, k_buf, v_buf, kkn_buf, a_buf,
                                      vg_buf, vfirst, k_k, k_a, r_k, rks_buf);

    scan_kernel<<<64, 512, 0, stream>>>(r_buf, w_buf, k_buf, kkn_buf, a_buf, v_buf,
                                        os_buf, state_out);

    elemwise2<<<NT, blk, 0, stream>>>(os_buf, rks_buf, v_buf, g_buf, gn_s, gn_b, kkn_buf);

    // y = z @ out_W
    gemm_mix<<<gBig, blk, 0, stream>>>(kkn_buf, nullptr, nullptr, out_W, nullptr, y_out, DD, DD, 0);

    // v_first passthrough
    hipMemcpyAsync(vf_out, vfirst, (size_t)NT * DD * sizeof(float),
                   hipMemcpyDeviceToDevice, stream);
}

// Round 3
// 1315.380 us; speedup vs baseline: 2.0461x; 2.0461x over previous
//
#include <hip/hip_runtime.h>
#include <math.h>

#define NT 4096      // B*T
#define DD 1024      // D == DM
#define NH 16
#define HSZ 64
#define GN_EPS 1e-5f
#define DECAY_C -0.606531f

typedef __attribute__((ext_vector_type(8))) short short8;
typedef __attribute__((ext_vector_type(4))) float float4v;

__device__ __forceinline__ float sigm(float x) { return 1.f / (1.f + __expf(-x)); }

__device__ __forceinline__ unsigned short f2bf(float f) {
    unsigned int u = __float_as_uint(f);
    u = (u + 0x7fffu + ((u >> 16) & 1u)) >> 16;
    return (unsigned short)u;
}
__device__ __forceinline__ float bf2f(unsigned short h) {
    return __uint_as_float(((unsigned int)h) << 16);
}

// ---------------- mix + split-cast for ONE branch: x = cur + lam*(prev-cur)
// writes hi (and lo residual if xl != nullptr)
__global__ __launch_bounds__(256)
void mix_split(const float* __restrict__ cur, const float* __restrict__ prev,
               const float* __restrict__ lam, ushort* __restrict__ xh,
               ushort* __restrict__ xl)
{
    const int tok = blockIdx.x;
    const int d0 = threadIdx.x * 4;
    const size_t base = (size_t)tok * DD + d0;
    float4 c = *(const float4*)(cur + base);
    float4 p = *(const float4*)(prev + base);
    float4 l = *(const float4*)(lam + d0);
    float m0 = c.x + l.x * (p.x - c.x);
    float m1 = c.y + l.y * (p.y - c.y);
    float m2 = c.z + l.z * (p.z - c.z);
    float m3 = c.w + l.w * (p.w - c.w);
    ushort4 h;
    h.x = f2bf(m0); h.y = f2bf(m1); h.z = f2bf(m2); h.w = f2bf(m3);
    *(ushort4*)(xh + base) = h;
    if (xl) {
        ushort4 lo;
        lo.x = f2bf(m0 - bf2f(h.x));
        lo.y = f2bf(m1 - bf2f(h.y));
        lo.z = f2bf(m2 - bf2f(h.z));
        lo.w = f2bf(m3 - bf2f(h.w));
        *(ushort4*)(xl + base) = lo;
    }
}

// ---------------- transpose + split-cast: W[K][N] fp32 -> Wt[N][K] hi/lo bf16
__global__ __launch_bounds__(256)
void transpose_split(const float* __restrict__ W, ushort* __restrict__ Wh,
                     ushort* __restrict__ Wl, int K, int N)
{
    __shared__ float tile[32][33];
    const int bx = blockIdx.x * 32;  // N
    const int by = blockIdx.y * 32;  // K
    const int tx = threadIdx.x, ty = threadIdx.y;  // 32 x 8
#pragma unroll
    for (int i = 0; i < 32; i += 8)
        tile[ty + i][tx] = W[(size_t)(by + ty + i) * N + bx + tx];
    __syncthreads();
#pragma unroll
    for (int i = 0; i < 32; i += 8) {
        float v = tile[tx][ty + i];
        ushort h = f2bf(v);
        size_t o = (size_t)(bx + ty + i) * K + by + tx;
        Wh[o] = h;
        if (Wl) Wl[o] = f2bf(v - bf2f(h));
    }
}

// ---------------- bf16(x3) MFMA GEMM: out[4096][N] = act(A[4096][K] @ W + bias)
// A, Bt split into hi/lo bf16 (lo nullable -> plain bf16 path).
// Output: outF fp32, else outH bf16 (+outL residual if non-null).
// act: 0 none, 1 tanh, 2 sigmoid.
__global__ __launch_bounds__(256)
void gemm_bf16s(const ushort* __restrict__ Ah, const ushort* __restrict__ Al,
                const ushort* __restrict__ Bh, const ushort* __restrict__ Bl,
                const float* __restrict__ bias,
                float* __restrict__ outF, ushort* __restrict__ outH,
                ushort* __restrict__ outL, int N, int K, int act)
{
    __shared__ ushort AsH[128 * 32];
    __shared__ ushort BsH[128 * 32];
    __shared__ ushort AsL[128 * 32];
    __shared__ ushort BsL[128 * 32];
    const bool split = (Al != nullptr);
    const int tid = threadIdx.x;
    const int rowBase = blockIdx.x * 128;
    const int colBase = blockIdx.y * 128;
    const int lane = tid & 63;
    const int wave = tid >> 6;
    const int wm = wave >> 1, wn = wave & 1;
    const int m15 = lane & 15, quad = lane >> 4;

    float4v zero4 = {0.f, 0.f, 0.f, 0.f};
    float4v acc[4][4];
#pragma unroll
    for (int i = 0; i < 4; i++)
#pragma unroll
        for (int j = 0; j < 4; j++) acc[i][j] = zero4;

    for (int k0 = 0; k0 < K; k0 += 32) {
#pragma unroll
        for (int i = 0; i < 2; i++) {
            int idx = i * 256 + tid;
            int r = idx >> 2, seg = idx & 3;
            size_t aoff = (size_t)(rowBase + r) * K + k0 + seg * 8;
            int rn = colBase + r; if (rn >= N) rn = N - 1;
            size_t boff = (size_t)rn * K + k0 + seg * 8;
            *(uint4*)(AsH + idx * 8) = *(const uint4*)(Ah + aoff);
            *(uint4*)(BsH + idx * 8) = *(const uint4*)(Bh + boff);
            if (split) {
                *(uint4*)(AsL + idx * 8) = *(const uint4*)(Al + aoff);
                *(uint4*)(BsL + idx * 8) = *(const uint4*)(Bl + boff);
            }
        }
        __syncthreads();
        short8 ah[4], bh[4];
#pragma unroll
        for (int mi = 0; mi < 4; mi++)
            ah[mi] = *(const short8*)(AsH + (wm * 64 + mi * 16 + m15) * 32 + quad * 8);
#pragma unroll
        for (int ni = 0; ni < 4; ni++)
            bh[ni] = *(const short8*)(BsH + (wn * 64 + ni * 16 + m15) * 32 + quad * 8);
        if (split) {
            short8 al[4], bl[4];
#pragma unroll
            for (int mi = 0; mi < 4; mi++)
                al[mi] = *(const short8*)(AsL + (wm * 64 + mi * 16 + m15) * 32 + quad * 8);
#pragma unroll
            for (int ni = 0; ni < 4; ni++)
                bl[ni] = *(const short8*)(BsL + (wn * 64 + ni * 16 + m15) * 32 + quad * 8);
#pragma unroll
            for (int mi = 0; mi < 4; mi++)
#pragma unroll
                for (int ni = 0; ni < 4; ni++) {
                    acc[mi][ni] = __builtin_amdgcn_mfma_f32_16x16x32_bf16(al[mi], bh[ni], acc[mi][ni], 0, 0, 0);
                    acc[mi][ni] = __builtin_amdgcn_mfma_f32_16x16x32_bf16(ah[mi], bl[ni], acc[mi][ni], 0, 0, 0);
                    acc[mi][ni] = __builtin_amdgcn_mfma_f32_16x16x32_bf16(ah[mi], bh[ni], acc[mi][ni], 0, 0, 0);
                }
        } else {
#pragma unroll
            for (int mi = 0; mi < 4; mi++)
#pragma unroll
                for (int ni = 0; ni < 4; ni++)
                    acc[mi][ni] = __builtin_amdgcn_mfma_f32_16x16x32_bf16(ah[mi], bh[ni], acc[mi][ni], 0, 0, 0);
        }
        __syncthreads();
    }

#pragma unroll
    for (int mi = 0; mi < 4; mi++) {
#pragma unroll
        for (int ni = 0; ni < 4; ni++) {
            int col = colBase + wn * 64 + ni * 16 + m15;
            if (col < N) {
                float bv = bias ? bias[col] : 0.f;
#pragma unroll
                for (int r = 0; r < 4; r++) {
                    int row = rowBase + wm * 64 + mi * 16 + quad * 4 + r;
                    float v = acc[mi][ni][r] + bv;
                    if (act == 1) v = tanhf(v);
                    else if (act == 2) v = sigm(v);
                    size_t o = (size_t)row * N + col;
                    if (outF) outF[o] = v;
                    else {
                        ushort h = f2bf(v);
                        outH[o] = h;
                        if (outL) outL[o] = f2bf(v - bf2f(h));
                    }
                }
            }
        }
    }
}

// ---------------- elementwise stage 1 (all fp32 — verified round 1)
__global__ __launch_bounds__(256)
void elemwise1(const float* __restrict__ r_buf, float* __restrict__ wl_buf,
               float* __restrict__ k_buf, float* __restrict__ v_buf,
               float* __restrict__ kkn_buf, const float* __restrict__ a_buf,
               const float* __restrict__ vg_buf, const float* __restrict__ vfirst,
               const float* __restrict__ kkw, const float* __restrict__ kaw,
               const float* __restrict__ rkw, float* __restrict__ rk_sum)
{
    const int tok = blockIdx.x;
    const int tid = threadIdx.x;
    const int d0 = tid * 4;
    const size_t base = (size_t)tok * DD + d0;

    float4 k0 = *(const float4*)(k_buf + base);
    float4 a4 = *(const float4*)(a_buf + base);
    float4 wl = *(const float4*)(wl_buf + base);
    float4 v0 = *(const float4*)(v_buf + base);
    float4 vg = *(const float4*)(vg_buf + base);
    float4 vf = *(const float4*)(vfirst + base);
    float4 r4 = *(const float4*)(r_buf + base);
    float4 kkc = *(const float4*)(kkw + d0);
    float4 kac = *(const float4*)(kaw + d0);
    float4 rkc = *(const float4*)(rkw + d0);

    float kk0 = k0.x * kkc.x, kk1 = k0.y * kkc.y, kk2 = k0.z * kkc.z, kk3 = k0.w * kkc.w;
    float ss = kk0 * kk0 + kk1 * kk1 + kk2 * kk2 + kk3 * kk3;
    ss += __shfl_xor(ss, 1); ss += __shfl_xor(ss, 2);
    ss += __shfl_xor(ss, 4); ss += __shfl_xor(ss, 8);
    float rn = rsqrtf(ss);
    float4 kkn = { kk0 * rn, kk1 * rn, kk2 * rn, kk3 * rn };
    *(float4*)(kkn_buf + base) = kkn;

    float4 kf;
    kf.x = k0.x * (1.f + (a4.x - 1.f) * kac.x);
    kf.y = k0.y * (1.f + (a4.y - 1.f) * kac.y);
    kf.z = k0.z * (1.f + (a4.z - 1.f) * kac.z);
    kf.w = k0.w * (1.f + (a4.w - 1.f) * kac.w);
    *(float4*)(k_buf + base) = kf;

    float rk = r4.x * kf.x * rkc.x + r4.y * kf.y * rkc.y + r4.z * kf.z * rkc.z + r4.w * kf.w * rkc.w;
    rk += __shfl_xor(rk, 1); rk += __shfl_xor(rk, 2);
    rk += __shfl_xor(rk, 4); rk += __shfl_xor(rk, 8);
    if ((tid & 15) == 0) rk_sum[(size_t)tok * NH + (tid >> 4)] = rk;

    float4 vfin;
    vfin.x = v0.x + (vf.x - v0.x) * vg.x;
    vfin.y = v0.y + (vf.y - v0.y) * vg.y;
    vfin.z = v0.z + (vf.z - v0.z) * vg.z;
    vfin.w = v0.w + (vf.w - v0.w) * vg.w;
    *(float4*)(v_buf + base) = vfin;

    float4 wd;
    wd.x = __expf(DECAY_C * sigm(wl.x));
    wd.y = __expf(DECAY_C * sigm(wl.y));
    wd.z = __expf(DECAY_C * sigm(wl.z));
    wd.w = __expf(DECAY_C * sigm(wl.w));
    *(float4*)(wl_buf + base) = wd;
}

// ---------------- sequential scan (all fp32 — verified round 1)
__global__ __launch_bounds__(512)
void scan_kernel(const float* __restrict__ r_buf, const float* __restrict__ w_buf,
                 const float* __restrict__ k_buf, const float* __restrict__ kkn_buf,
                 const float* __restrict__ a_buf, const float* __restrict__ v_buf,
                 float* __restrict__ out_scan, float* __restrict__ state_out)
{
    __shared__ float buf[2][384];  // [r|w|k|kk|a|v] x 64
    const int bh = blockIdx.x;
    const int b = bh >> 4, h = bh & 15;
    const int tid = threadIdx.x;
    const int row = tid >> 3, q = tid & 7;
    float s[8] = {};
    const size_t tok0 = ((size_t)b * 1024) * DD + h * HSZ;

    const float* src = nullptr;
    int dsto = 0;
    if (tid < 96) {
        int arr = tid >> 4;
        int e = (tid & 15) * 4;
        const float* bs;
        if (arr == 0) bs = r_buf;
        else if (arr == 1) bs = w_buf;
        else if (arr == 2) bs = k_buf;
        else if (arr == 3) bs = kkn_buf;
        else if (arr == 4) bs = a_buf;
        else bs = v_buf;
        src = bs + tok0 + e;
        dsto = arr * 64 + e;
        *(float4*)&buf[0][dsto] = *(const float4*)src;
        src += DD;
    }
    __syncthreads();

    int p = 0;
    float* yout = out_scan + tok0 + row;
    for (int t = 0; t < 1024; t++) {
        float4 nv;
        const bool more = (src != nullptr) && (t < 1023);
        if (more) nv = *(const float4*)src;

        const float* bp = buf[p];
        float rr[8], ww[8], kv[8], kn[8], aa[8];
        *(float4*)&rr[0] = *(const float4*)&bp[q * 8];
        *(float4*)&rr[4] = *(const float4*)&bp[q * 8 + 4];
        *(float4*)&ww[0] = *(const float4*)&bp[64 + q * 8];
        *(float4*)&ww[4] = *(const float4*)&bp[64 + q * 8 + 4];
        *(float4*)&kv[0] = *(const float4*)&bp[128 + q * 8];
        *(float4*)&kv[4] = *(const float4*)&bp[128 + q * 8 + 4];
        *(float4*)&kn[0] = *(const float4*)&bp[192 + q * 8];
        *(float4*)&kn[4] = *(const float4*)&bp[192 + q * 8 + 4];
        *(float4*)&aa[0] = *(const float4*)&bp[256 + q * 8];
        *(float4*)&aa[4] = *(const float4*)&bp[256 + q * 8 + 4];
        float vv = bp[320 + row];

        float sa = 0.f;
#pragma unroll
        for (int j = 0; j < 8; j++) sa += s[j] * kn[j];
        sa = -sa;
        sa += __shfl_xor(sa, 1); sa += __shfl_xor(sa, 2); sa += __shfl_xor(sa, 4);

        float y = 0.f;
#pragma unroll
        for (int j = 0; j < 8; j++) {
            float bt = kn[j] * aa[j];
            s[j] = s[j] * ww[j] + sa * bt + vv * kv[j];
            y += s[j] * rr[j];
        }
        y += __shfl_xor(y, 1); y += __shfl_xor(y, 2); y += __shfl_xor(y, 4);
        if (q == 0) yout[(size_t)t * DD] = y;

        if (more) {
            *(float4*)&buf[1 - p][dsto] = nv;
            src += DD;
        }
        __syncthreads();
        p ^= 1;
    }

    float* so = state_out + ((size_t)(b * NH + h) * HSZ + row) * HSZ + q * 8;
    *(float4*)so = *(float4*)&s[0];
    *(float4*)(so + 4) = *(float4*)&s[4];
}

// ---------------- stage 2: GroupNorm + residual + gate -> z (plain bf16)
__global__ __launch_bounds__(256)
void elemwise2(const float* __restrict__ out_scan, const float* __restrict__ rk_sum,
               const float* __restrict__ v_buf, const float* __restrict__ g_buf,
               const float* __restrict__ gscale, const float* __restrict__ gbias,
               ushort* __restrict__ z_buf)
{
    const int tok = blockIdx.x;
    const int tid = threadIdx.x;
    const int d0 = tid * 4;
    const size_t base = (size_t)tok * DD + d0;

    float4 o = *(const float4*)(out_scan + base);
    float sm = o.x + o.y + o.z + o.w;
    float ss = o.x * o.x + o.y * o.y + o.z * o.z + o.w * o.w;
    sm += __shfl_xor(sm, 1); sm += __shfl_xor(sm, 2);
    sm += __shfl_xor(sm, 4); sm += __shfl_xor(sm, 8);
    ss += __shfl_xor(ss, 1); ss += __shfl_xor(ss, 2);
    ss += __shfl_xor(ss, 4); ss += __shfl_xor(ss, 8);
    float mu = sm * (1.f / 64.f);
    float var = ss * (1.f / 64.f) - mu * mu;
    float rs = rsqrtf(var + GN_EPS);
    float rk = rk_sum[(size_t)tok * NH + (tid >> 4)];

    float4 v4 = *(const float4*)(v_buf + base);
    float4 g4 = *(const float4*)(g_buf + base);
    float4 gs = *(const float4*)(gscale + d0);
    float4 gb = *(const float4*)(gbias + d0);
    ushort4 z;
    z.x = f2bf(((o.x - mu) * rs * gs.x + gb.x + rk * v4.x) * g4.x);
    z.y = f2bf(((o.y - mu) * rs * gs.y + gb.y + rk * v4.y) * g4.y);
    z.z = f2bf(((o.z - mu) * rs * gs.z + gb.z + rk * v4.z) * g4.z);
    z.w = f2bf(((o.w - mu) * rs * gs.w + gb.w + rk * v4.w) * g4.w);
    *(ushort4*)(z_buf + base) = z;
}

extern "C" void kernel_launch(void* const* d_in, const int* in_sizes, int n_in,
                              void* d_out, int out_size, void* d_ws, size_t ws_size,
                              hipStream_t stream) {
    const float* cur    = (const float*)d_in[0];
    const float* prev   = (const float*)d_in[1];
    const float* vfirst = (const float*)d_in[2];
    const float* rwkvag = (const float*)d_in[3];
    const float* rw_W   = (const float*)d_in[4];
    const float* w1     = (const float*)d_in[5];
    const float* w2     = (const float*)d_in[6];
    const float* w2_b   = (const float*)d_in[7];
    const float* kw_W   = (const float*)d_in[8];
    const float* vw_W   = (const float*)d_in[9];
    const float* a1     = (const float*)d_in[10];
    const float* a2     = (const float*)d_in[11];
    const float* a2_b   = (const float*)d_in[12];
    const float* v1     = (const float*)d_in[13];
    const float* v2     = (const float*)d_in[14];
    const float* v2_b   = (const float*)d_in[15];
    const float* g1     = (const float*)d_in[16];
    const float* g2     = (const float*)d_in[17];
    const float* g2_b   = (const float*)d_in[18];
    const float* k_k    = (const float*)d_in[19];
    const float* k_a    = (const float*)d_in[20];
    const float* r_k    = (const float*)d_in[21];
    const float* gn_s   = (const float*)d_in[22];
    const float* gn_b   = (const float*)d_in[23];
    const float* out_W  = (const float*)d_in[24];

    float* out = (float*)d_out;
    float* y_out = out;                                  // 4096*1024 fp32
    float* state_out = out + (size_t)NT * DD;            // 4*16*64*64 fp32
    float* vf_out = state_out + (size_t)4 * NH * HSZ * HSZ;

    // ---- workspace carve (float units). ~166 MB total.
    float* p = (float*)d_ws;
    const size_t big = (size_t)NT * DD;   // 4,194,304 floats
    const size_t half = big / 2;          // one big bf16 array, in float units
    float* r_buf = p;   p += big;
    float* w_buf = p;   p += big;   // wl -> wdec in place
    float* k_buf = p;   p += big;   // k0 -> k final in place
    float* v_buf = p;   p += big;   // v0 -> v final in place
    float* kkn_buf = p; p += big;
    float* a_buf = p;   p += big;
    float* vg_buf = p;  p += big;   // dead after elemwise1 -> reused as out_scan
    float* os_buf = vg_buf;
    float* g_buf = p;   p += big;
    ushort* xh = (ushort*)p; p += half;   // shared per-branch mix scratch
    ushort* xl = (ushort*)p; p += half;
    ushort* z_bf = xh;                    // z overlays xh (x dead post stage-1)
    const size_t WBIG = 524288;           // 1024x1024 bf16, float units
    ushort* rwTh = (ushort*)p; p += WBIG;  ushort* rwTl = (ushort*)p; p += WBIG;
    ushort* kwTh = (ushort*)p; p += WBIG;  ushort* kwTl = (ushort*)p; p += WBIG;
    ushort* vwTh = (ushort*)p; p += WBIG;  ushort* vwTl = (ushort*)p; p += WBIG;
    ushort* outTh = (ushort*)p; p += WBIG;              // plain (no lo)
    ushort* w1Th = (ushort*)p; p += 32768; ushort* w1Tl = (ushort*)p; p += 32768;
    ushort* a1Th = (ushort*)p; p += 32768; ushort* a1Tl = (ushort*)p; p += 32768;
    ushort* v1Th = (ushort*)p; p += 16384; ushort* v1Tl = (ushort*)p; p += 16384;
    ushort* g1Th = (ushort*)p; p += 65536;              // plain
    ushort* w2Th = (ushort*)p; p += 32768; ushort* w2Tl = (ushort*)p; p += 32768;
    ushort* a2Th = (ushort*)p; p += 32768; ushort* a2Tl = (ushort*)p; p += 32768;
    ushort* v2Th = (ushort*)p; p += 16384; ushort* v2Tl = (ushort*)p; p += 16384;
    ushort* g2Th = (ushort*)p; p += 65536;              // plain
    ushort* hwh = (ushort*)p; p += 131072; ushort* hwl = (ushort*)p; p += 131072;
    ushort* hah = (ushort*)p; p += 131072; ushort* hal = (ushort*)p; p += 131072;
    ushort* hvh = (ushort*)p; p += 65536;  ushort* hvl = (ushort*)p; p += 65536;
    ushort* hgh = (ushort*)p; p += 262144;              // plain
    float* rks_buf = p;        p += 65536;

    dim3 blk(256);
    dim3 t32x8(32, 8);

    // ---- weight transposes (split except g path / out_W)
    transpose_split<<<dim3(32, 32), t32x8, 0, stream>>>(rw_W, rwTh, rwTl, 1024, 1024);
    transpose_split<<<dim3(32, 32), t32x8, 0, stream>>>(kw_W, kwTh, kwTl, 1024, 1024);
    transpose_split<<<dim3(32, 32), t32x8, 0, stream>>>(vw_W, vwTh, vwTl, 1024, 1024);
    transpose_split<<<dim3(32, 32), t32x8, 0, stream>>>(out_W, outTh, nullptr, 1024, 1024);
    transpose_split<<<dim3(2, 32), t32x8, 0, stream>>>(w1, w1Th, w1Tl, 1024, 64);
    transpose_split<<<dim3(2, 32), t32x8, 0, stream>>>(a1, a1Th, a1Tl, 1024, 64);
    transpose_split<<<dim3(1, 32), t32x8, 0, stream>>>(v1, v1Th, v1Tl, 1024, 32);
    transpose_split<<<dim3(4, 32), t32x8, 0, stream>>>(g1, g1Th, nullptr, 1024, 128);
    transpose_split<<<dim3(32, 2), t32x8, 0, stream>>>(w2, w2Th, w2Tl, 64, 1024);
    transpose_split<<<dim3(32, 2), t32x8, 0, stream>>>(a2, a2Th, a2Tl, 64, 1024);
    transpose_split<<<dim3(32, 1), t32x8, 0, stream>>>(v2, v2Th, v2Tl, 32, 1024);
    transpose_split<<<dim3(32, 4), t32x8, 0, stream>>>(g2, g2Th, nullptr, 128, 1024);

    dim3 gBig(32, 8), gN1(32, 1);

    // ---- branch r
    mix_split<<<NT, blk, 0, stream>>>(cur, prev, rwkvag + 0 * DD, xh, xl);
    gemm_bf16s<<<gBig, blk, 0, stream>>>(xh, xl, rwTh, rwTl, nullptr, r_buf, nullptr, nullptr, 1024, 1024, 0);
    // ---- branch w (LoRA stage 1, tanh, split hidden)
    mix_split<<<NT, blk, 0, stream>>>(cur, prev, rwkvag + 1 * DD, xh, xl);
    gemm_bf16s<<<gN1, blk, 0, stream>>>(xh, xl, w1Th, w1Tl, nullptr, nullptr, hwh, hwl, 64, 1024, 1);
    // ---- branch k
    mix_split<<<NT, blk, 0, stream>>>(cur, prev, rwkvag + 2 * DD, xh, xl);
    gemm_bf16s<<<gBig, blk, 0, stream>>>(xh, xl, kwTh, kwTl, nullptr, k_buf, nullptr, nullptr, 1024, 1024, 0);
    // ---- branch v (big GEMM + v-gate LoRA stage 1)
    mix_split<<<NT, blk, 0, stream>>>(cur, prev, rwkvag + 3 * DD, xh, xl);
    gemm_bf16s<<<gBig, blk, 0, stream>>>(xh, xl, vwTh, vwTl, nullptr, v_buf, nullptr, nullptr, 1024, 1024, 0);
    gemm_bf16s<<<gN1, blk, 0, stream>>>(xh, xl, v1Th, v1Tl, nullptr, nullptr, hvh, hvl, 32, 1024, 0);
    // ---- branch a (LoRA stage 1)
    mix_split<<<NT, blk, 0, stream>>>(cur, prev, rwkvag + 4 * DD, xh, xl);
    gemm_bf16s<<<gN1, blk, 0, stream>>>(xh, xl, a1Th, a1Tl, nullptr, nullptr, hah, hal, 64, 1024, 0);
    // ---- branch g (plain bf16 path, sigmoid hidden)
    mix_split<<<NT, blk, 0, stream>>>(cur, prev, rwkvag + 5 * DD, xh, nullptr);
    gemm_bf16s<<<gN1, blk, 0, stream>>>(xh, nullptr, g1Th, nullptr, nullptr, nullptr, hgh, nullptr, 128, 1024, 2);

    // ---- LoRA stage 2
    gemm_bf16s<<<gBig, blk, 0, stream>>>(hwh, hwl, w2Th, w2Tl, w2_b, w_buf, nullptr, nullptr, 1024, 64, 0);
    gemm_bf16s<<<gBig, blk, 0, stream>>>(hah, hal, a2Th, a2Tl, a2_b, a_buf, nullptr, nullptr, 1024, 64, 2);
    gemm_bf16s<<<gBig, blk, 0, stream>>>(hvh, hvl, v2Th, v2Tl, v2_b, vg_buf, nullptr, nullptr, 1024, 32, 2);
    gemm_bf16s<<<gBig, blk, 0, stream>>>(hgh, nullptr, g2Th, nullptr, g2_b, g_buf, nullptr, nullptr, 1024, 128, 0);

    // ---- elementwise + scan + epilogue
    elemwise1<<<NT, blk, 0, stream>>>(r_buf, w_buf, k_buf, v_buf, kkn_buf, a_buf,
                                      vg_buf, vfirst, k_k, k_a, r_k, rks_buf);

    scan_kernel<<<64, 512, 0, stream>>>(r_buf, w_buf, k_buf, kkn_buf, a_buf, v_buf,
                                        os_buf, state_out);

    elemwise2<<<NT, blk, 0, stream>>>(os_buf, rks_buf, v_buf, g_buf, gn_s, gn_b, z_bf);

    // ---- y = z @ out_W (plain bf16)
    gemm_bf16s<<<gBig, blk, 0, stream>>>(z_bf, nullptr, outTh, nullptr, nullptr, y_out, nullptr, nullptr, 1024, 1024, 0);

    // ---- v_first passthrough
    hipMemcpyAsync(vf_out, vfirst, (size_t)NT * DD * sizeof(float),
                   hipMemcpyDeviceToDevice, stream);
}

// Round 4
// 1170.288 us; speedup vs baseline: 2.2997x; 1.1240x over previous
//
#include <hip/hip_runtime.h>
#include <math.h>

#define NT 4096      // B*T
#define DD 1024      // D == DM
#define NH 16
#define HSZ 64
#define GN_EPS 1e-5f
#define DECAY_C -0.606531f

typedef __attribute__((ext_vector_type(8))) short short8;
typedef __attribute__((ext_vector_type(4))) float float4v;

__device__ __forceinline__ float sigm(float x) { return 1.f / (1.f + __expf(-x)); }

__device__ __forceinline__ unsigned short f2bf(float f) {
    unsigned int u = __float_as_uint(f);
    u = (u + 0x7fffu + ((u >> 16) & 1u)) >> 16;
    return (unsigned short)u;
}
__device__ __forceinline__ float bf2f(unsigned short h) {
    return __uint_as_float(((unsigned int)h) << 16);
}

// ---------------- mix + split-cast for ONE branch: x = cur + lam*(prev-cur)
__global__ __launch_bounds__(256)
void mix_split(const float* __restrict__ cur, const float* __restrict__ prev,
               const float* __restrict__ lam, ushort* __restrict__ xh,
               ushort* __restrict__ xl)
{
    const int tok = blockIdx.x;
    const int d0 = threadIdx.x * 4;
    const size_t base = (size_t)tok * DD + d0;
    float4 c = *(const float4*)(cur + base);
    float4 p = *(const float4*)(prev + base);
    float4 l = *(const float4*)(lam + d0);
    float m0 = c.x + l.x * (p.x - c.x);
    float m1 = c.y + l.y * (p.y - c.y);
    float m2 = c.z + l.z * (p.z - c.z);
    float m3 = c.w + l.w * (p.w - c.w);
    ushort4 h;
    h.x = f2bf(m0); h.y = f2bf(m1); h.z = f2bf(m2); h.w = f2bf(m3);
    *(ushort4*)(xh + base) = h;
    if (xl) {
        ushort4 lo;
        lo.x = f2bf(m0 - bf2f(h.x));
        lo.y = f2bf(m1 - bf2f(h.y));
        lo.z = f2bf(m2 - bf2f(h.z));
        lo.w = f2bf(m3 - bf2f(h.w));
        *(ushort4*)(xl + base) = lo;
    }
}

// ---------------- transpose + split-cast: W[K][N] fp32 -> Wt[N][K] hi/lo bf16
__global__ __launch_bounds__(256)
void transpose_split(const float* __restrict__ W, ushort* __restrict__ Wh,
                     ushort* __restrict__ Wl, int K, int N)
{
    __shared__ float tile[32][33];
    const int bx = blockIdx.x * 32;  // N
    const int by = blockIdx.y * 32;  // K
    const int tx = threadIdx.x, ty = threadIdx.y;  // 32 x 8
#pragma unroll
    for (int i = 0; i < 32; i += 8)
        tile[ty + i][tx] = W[(size_t)(by + ty + i) * N + bx + tx];
    __syncthreads();
#pragma unroll
    for (int i = 0; i < 32; i += 8) {
        float v = tile[tx][ty + i];
        ushort h = f2bf(v);
        size_t o = (size_t)(bx + ty + i) * K + by + tx;
        Wh[o] = h;
        if (Wl) Wl[o] = f2bf(v - bf2f(h));
    }
}

// ---------------- bf16(x3) MFMA GEMM: out[4096][N] = act(A[4096][K] @ W + bias)
__global__ __launch_bounds__(256)
void gemm_bf16s(const ushort* __restrict__ Ah, const ushort* __restrict__ Al,
                const ushort* __restrict__ Bh, const ushort* __restrict__ Bl,
                const float* __restrict__ bias,
                float* __restrict__ outF, ushort* __restrict__ outH,
                ushort* __restrict__ outL, int N, int K, int act)
{
    __shared__ ushort AsH[128 * 32];
    __shared__ ushort BsH[128 * 32];
    __shared__ ushort AsL[128 * 32];
    __shared__ ushort BsL[128 * 32];
    const bool split = (Al != nullptr);
    const int tid = threadIdx.x;
    const int rowBase = blockIdx.x * 128;
    const int colBase = blockIdx.y * 128;
    const int lane = tid & 63;
    const int wave = tid >> 6;
    const int wm = wave >> 1, wn = wave & 1;
    const int m15 = lane & 15, quad = lane >> 4;

    float4v zero4 = {0.f, 0.f, 0.f, 0.f};
    float4v acc[4][4];
#pragma unroll
    for (int i = 0; i < 4; i++)
#pragma unroll
        for (int j = 0; j < 4; j++) acc[i][j] = zero4;

    for (int k0 = 0; k0 < K; k0 += 32) {
#pragma unroll
        for (int i = 0; i < 2; i++) {
            int idx = i * 256 + tid;
            int r = idx >> 2, seg = idx & 3;
            size_t aoff = (size_t)(rowBase + r) * K + k0 + seg * 8;
            int rn = colBase + r; if (rn >= N) rn = N - 1;
            size_t boff = (size_t)rn * K + k0 + seg * 8;
            *(uint4*)(AsH + idx * 8) = *(const uint4*)(Ah + aoff);
            *(uint4*)(BsH + idx * 8) = *(const uint4*)(Bh + boff);
            if (split) {
                *(uint4*)(AsL + idx * 8) = *(const uint4*)(Al + aoff);
                *(uint4*)(BsL + idx * 8) = *(const uint4*)(Bl + boff);
            }
        }
        __syncthreads();
        short8 ah[4], bh[4];
#pragma unroll
        for (int mi = 0; mi < 4; mi++)
            ah[mi] = *(const short8*)(AsH + (wm * 64 + mi * 16 + m15) * 32 + quad * 8);
#pragma unroll
        for (int ni = 0; ni < 4; ni++)
            bh[ni] = *(const short8*)(BsH + (wn * 64 + ni * 16 + m15) * 32 + quad * 8);
        if (split) {
            short8 al[4], bl[4];
#pragma unroll
            for (int mi = 0; mi < 4; mi++)
                al[mi] = *(const short8*)(AsL + (wm * 64 + mi * 16 + m15) * 32 + quad * 8);
#pragma unroll
            for (int ni = 0; ni < 4; ni++)
                bl[ni] = *(const short8*)(BsL + (wn * 64 + ni * 16 + m15) * 32 + quad * 8);
#pragma unroll
            for (int mi = 0; mi < 4; mi++)
#pragma unroll
                for (int ni = 0; ni < 4; ni++) {
                    acc[mi][ni] = __builtin_amdgcn_mfma_f32_16x16x32_bf16(al[mi], bh[ni], acc[mi][ni], 0, 0, 0);
                    acc[mi][ni] = __builtin_amdgcn_mfma_f32_16x16x32_bf16(ah[mi], bl[ni], acc[mi][ni], 0, 0, 0);
                    acc[mi][ni] = __builtin_amdgcn_mfma_f32_16x16x32_bf16(ah[mi], bh[ni], acc[mi][ni], 0, 0, 0);
                }
        } else {
#pragma unroll
            for (int mi = 0; mi < 4; mi++)
#pragma unroll
                for (int ni = 0; ni < 4; ni++)
                    acc[mi][ni] = __builtin_amdgcn_mfma_f32_16x16x32_bf16(ah[mi], bh[ni], acc[mi][ni], 0, 0, 0);
        }
        __syncthreads();
    }

#pragma unroll
    for (int mi = 0; mi < 4; mi++) {
#pragma unroll
        for (int ni = 0; ni < 4; ni++) {
            int col = colBase + wn * 64 + ni * 16 + m15;
            if (col < N) {
                float bv = bias ? bias[col] : 0.f;
#pragma unroll
                for (int r = 0; r < 4; r++) {
                    int row = rowBase + wm * 64 + mi * 16 + quad * 4 + r;
                    float v = acc[mi][ni][r] + bv;
                    if (act == 1) v = tanhf(v);
                    else if (act == 2) v = sigm(v);
                    size_t o = (size_t)row * N + col;
                    if (outF) outF[o] = v;
                    else {
                        ushort h = f2bf(v);
                        outH[o] = h;
                        if (outL) outL[o] = f2bf(v - bf2f(h));
                    }
                }
            }
        }
    }
}

// ---------------- elementwise stage 1 (fp32)
__global__ __launch_bounds__(256)
void elemwise1(const float* __restrict__ r_buf, float* __restrict__ wl_buf,
               float* __restrict__ k_buf, float* __restrict__ v_buf,
               float* __restrict__ kkn_buf, const float* __restrict__ a_buf,
               const float* __restrict__ vg_buf, const float* __restrict__ vfirst,
               const float* __restrict__ kkw, const float* __restrict__ kaw,
               const float* __restrict__ rkw, float* __restrict__ rk_sum)
{
    const int tok = blockIdx.x;
    const int tid = threadIdx.x;
    const int d0 = tid * 4;
    const size_t base = (size_t)tok * DD + d0;

    float4 k0 = *(const float4*)(k_buf + base);
    float4 a4 = *(const float4*)(a_buf + base);
    float4 wl = *(const float4*)(wl_buf + base);
    float4 v0 = *(const float4*)(v_buf + base);
    float4 vg = *(const float4*)(vg_buf + base);
    float4 vf = *(const float4*)(vfirst + base);
    float4 r4 = *(const float4*)(r_buf + base);
    float4 kkc = *(const float4*)(kkw + d0);
    float4 kac = *(const float4*)(kaw + d0);
    float4 rkc = *(const float4*)(rkw + d0);

    float kk0 = k0.x * kkc.x, kk1 = k0.y * kkc.y, kk2 = k0.z * kkc.z, kk3 = k0.w * kkc.w;
    float ss = kk0 * kk0 + kk1 * kk1 + kk2 * kk2 + kk3 * kk3;
    ss += __shfl_xor(ss, 1); ss += __shfl_xor(ss, 2);
    ss += __shfl_xor(ss, 4); ss += __shfl_xor(ss, 8);
    float rn = rsqrtf(ss);
    float4 kkn = { kk0 * rn, kk1 * rn, kk2 * rn, kk3 * rn };
    *(float4*)(kkn_buf + base) = kkn;

    float4 kf;
    kf.x = k0.x * (1.f + (a4.x - 1.f) * kac.x);
    kf.y = k0.y * (1.f + (a4.y - 1.f) * kac.y);
    kf.z = k0.z * (1.f + (a4.z - 1.f) * kac.z);
    kf.w = k0.w * (1.f + (a4.w - 1.f) * kac.w);
    *(float4*)(k_buf + base) = kf;

    float rk = r4.x * kf.x * rkc.x + r4.y * kf.y * rkc.y + r4.z * kf.z * rkc.z + r4.w * kf.w * rkc.w;
    rk += __shfl_xor(rk, 1); rk += __shfl_xor(rk, 2);
    rk += __shfl_xor(rk, 4); rk += __shfl_xor(rk, 8);
    if ((tid & 15) == 0) rk_sum[(size_t)tok * NH + (tid >> 4)] = rk;

    float4 vfin;
    vfin.x = v0.x + (vf.x - v0.x) * vg.x;
    vfin.y = v0.y + (vf.y - v0.y) * vg.y;
    vfin.z = v0.z + (vf.z - v0.z) * vg.z;
    vfin.w = v0.w + (vf.w - v0.w) * vg.w;
    *(float4*)(v_buf + base) = vfin;

    float4 wd;
    wd.x = __expf(DECAY_C * sigm(wl.x));
    wd.y = __expf(DECAY_C * sigm(wl.y));
    wd.z = __expf(DECAY_C * sigm(wl.z));
    wd.w = __expf(DECAY_C * sigm(wl.w));
    *(float4*)(wl_buf + base) = wd;
}

// ---------------- sequential scan, row-split + chunked staging.
// grid (64 bh, 4 rowgroups), 256 threads: 16 rows x 16 lanes, 4 state elems/thread.
// Chunk of 16 steps staged into LDS; 2 barriers per chunk (none per step).
__global__ __launch_bounds__(256)
void scan_kernel(const float* __restrict__ r_buf, const float* __restrict__ w_buf,
                 const float* __restrict__ k_buf, const float* __restrict__ kkn_buf,
                 const float* __restrict__ a_buf, const float* __restrict__ v_buf,
                 float* __restrict__ out_scan, float* __restrict__ state_out)
{
    __shared__ float vec[16][5][64];   // [t][r|w|k|kk|a][64]  20 KB
    __shared__ float vbuf[16][16];     // [t][16 rows]          1 KB
    __shared__ float ybuf[16][16];     // [t][16 rows]          1 KB
    const int bh = blockIdx.x;
    const int rg = blockIdx.y;
    const int b = bh >> 4, h = bh & 15;
    const int tid = threadIdx.x;
    const int row = tid >> 4, l16 = tid & 15;
    const int rowbase = rg * 16;
    const size_t tok0 = ((size_t)b * 1024) * DD + h * HSZ;
    float s0 = 0.f, s1 = 0.f, s2 = 0.f, s3 = 0.f;

    const int tld = tid >> 4;          // which t this thread stages
    const int lld = (tid & 15) * 4;    // element offset in the 64-vec

    for (int c = 0; c < 64; c++) {
        // flush previous chunk's y, stage chunk c (same barrier window)
        if (c > 0 && tid < 64) {
            int t = tid >> 2, l4 = (tid & 3) * 4;
            float4 yv = *(float4*)&ybuf[t][l4];
            *(float4*)(out_scan + tok0 + (size_t)((c - 1) * 16 + t) * DD + rowbase + l4) = yv;
        }
#pragma unroll
        for (int j = 0; j < 5; j++) {
            const float* bs = (j == 0) ? r_buf : (j == 1) ? w_buf : (j == 2) ? k_buf
                              : (j == 3) ? kkn_buf : a_buf;
            *(float4*)&vec[tld][j][lld] =
                *(const float4*)(bs + tok0 + (size_t)(c * 16 + tld) * DD + lld);
        }
        if (tid < 64) {
            int t = tid >> 2, l4 = (tid & 3) * 4;
            *(float4*)&vbuf[t][l4] =
                *(const float4*)(v_buf + tok0 + (size_t)(c * 16 + t) * DD + rowbase + l4);
        }
        __syncthreads();

        for (int t = 0; t < 16; t++) {
            const float* vp = &vec[t][0][0];
            float4 r4 = *(const float4*)(vp + l16 * 4);
            float4 w4 = *(const float4*)(vp + 64 + l16 * 4);
            float4 k4 = *(const float4*)(vp + 128 + l16 * 4);
            float4 q4 = *(const float4*)(vp + 192 + l16 * 4);  // kk
            float4 a4 = *(const float4*)(vp + 256 + l16 * 4);
            float vv = vbuf[t][row];

            float sa = s0 * q4.x + s1 * q4.y + s2 * q4.z + s3 * q4.w;
            sa += __shfl_xor(sa, 1); sa += __shfl_xor(sa, 2);
            sa += __shfl_xor(sa, 4); sa += __shfl_xor(sa, 8);
            sa = -sa;  // at = -kk

            s0 = s0 * w4.x + sa * (q4.x * a4.x) + vv * k4.x;
            s1 = s1 * w4.y + sa * (q4.y * a4.y) + vv * k4.y;
            s2 = s2 * w4.z + sa * (q4.z * a4.z) + vv * k4.z;
            s3 = s3 * w4.w + sa * (q4.w * a4.w) + vv * k4.w;

            float y = s0 * r4.x + s1 * r4.y + s2 * r4.z + s3 * r4.w;
            y += __shfl_xor(y, 1); y += __shfl_xor(y, 2);
            y += __shfl_xor(y, 4); y += __shfl_xor(y, 8);
            if (l16 == 0) ybuf[t][row] = y;
        }
        __syncthreads();
    }

    // final flush (chunk 63)
    if (tid < 64) {
        int t = tid >> 2, l4 = (tid & 3) * 4;
        float4 yv = *(float4*)&ybuf[t][l4];
        *(float4*)(out_scan + tok0 + (size_t)(1008 + t) * DD + rowbase + l4) = yv;
    }

    float* so = state_out + ((size_t)(b * NH + h) * HSZ + rowbase + row) * HSZ + l16 * 4;
    float4 sv = {s0, s1, s2, s3};
    *(float4*)so = sv;
}

// ---------------- stage 2: GroupNorm + residual + gate -> z (plain bf16)
__global__ __launch_bounds__(256)
void elemwise2(const float* __restrict__ out_scan, const float* __restrict__ rk_sum,
               const float* __restrict__ v_buf, const float* __restrict__ g_buf,
               const float* __restrict__ gscale, const float* __restrict__ gbias,
               ushort* __restrict__ z_buf)
{
    const int tok = blockIdx.x;
    const int tid = threadIdx.x;
    const int d0 = tid * 4;
    const size_t base = (size_t)tok * DD + d0;

    float4 o = *(const float4*)(out_scan + base);
    float sm = o.x + o.y + o.z + o.w;
    float ss = o.x * o.x + o.y * o.y + o.z * o.z + o.w * o.w;
    sm += __shfl_xor(sm, 1); sm += __shfl_xor(sm, 2);
    sm += __shfl_xor(sm, 4); sm += __shfl_xor(sm, 8);
    ss += __shfl_xor(ss, 1); ss += __shfl_xor(ss, 2);
    ss += __shfl_xor(ss, 4); ss += __shfl_xor(ss, 8);
    float mu = sm * (1.f / 64.f);
    float var = ss * (1.f / 64.f) - mu * mu;
    float rs = rsqrtf(var + GN_EPS);
    float rk = rk_sum[(size_t)tok * NH + (tid >> 4)];

    float4 v4 = *(const float4*)(v_buf + base);
    float4 g4 = *(const float4*)(g_buf + base);
    float4 gs = *(const float4*)(gscale + d0);
    float4 gb = *(const float4*)(gbias + d0);
    ushort4 z;
    z.x = f2bf(((o.x - mu) * rs * gs.x + gb.x + rk * v4.x) * g4.x);
    z.y = f2bf(((o.y - mu) * rs * gs.y + gb.y + rk * v4.y) * g4.y);
    z.z = f2bf(((o.z - mu) * rs * gs.z + gb.z + rk * v4.z) * g4.z);
    z.w = f2bf(((o.w - mu) * rs * gs.w + gb.w + rk * v4.w) * g4.w);
    *(ushort4*)(z_buf + base) = z;
}

extern "C" void kernel_launch(void* const* d_in, const int* in_sizes, int n_in,
                              void* d_out, int out_size, void* d_ws, size_t ws_size,
                              hipStream_t stream) {
    const float* cur    = (const float*)d_in[0];
    const float* prev   = (const float*)d_in[1];
    const float* vfirst = (const float*)d_in[2];
    const float* rwkvag = (const float*)d_in[3];
    const float* rw_W   = (const float*)d_in[4];
    const float* w1     = (const float*)d_in[5];
    const float* w2     = (const float*)d_in[6];
    const float* w2_b   = (const float*)d_in[7];
    const float* kw_W   = (const float*)d_in[8];
    const float* vw_W   = (const float*)d_in[9];
    const float* a1     = (const float*)d_in[10];
    const float* a2     = (const float*)d_in[11];
    const float* a2_b   = (const float*)d_in[12];
    const float* v1     = (const float*)d_in[13];
    const float* v2     = (const float*)d_in[14];
    const float* v2_b   = (const float*)d_in[15];
    const float* g1     = (const float*)d_in[16];
    const float* g2     = (const float*)d_in[17];
    const float* g2_b   = (const float*)d_in[18];
    const float* k_k    = (const float*)d_in[19];
    const float* k_a    = (const float*)d_in[20];
    const float* r_k    = (const float*)d_in[21];
    const float* gn_s   = (const float*)d_in[22];
    const float* gn_b   = (const float*)d_in[23];
    const float* out_W  = (const float*)d_in[24];

    float* out = (float*)d_out;
    float* y_out = out;                                  // 4096*1024 fp32
    float* state_out = out + (size_t)NT * DD;            // 4*16*64*64 fp32
    float* vf_out = state_out + (size_t)4 * NH * HSZ * HSZ;

    // ---- workspace carve (float units). ~166 MB total.
    float* p = (float*)d_ws;
    const size_t big = (size_t)NT * DD;   // 4,194,304 floats
    const size_t half = big / 2;          // one big bf16 array, in float units
    float* r_buf = p;   p += big;
    float* w_buf = p;   p += big;   // wl -> wdec in place
    float* k_buf = p;   p += big;   // k0 -> k final in place
    float* v_buf = p;   p += big;   // v0 -> v final in place
    float* kkn_buf = p; p += big;
    float* a_buf = p;   p += big;
    float* vg_buf = p;  p += big;   // dead after elemwise1 -> reused as out_scan
    float* os_buf = vg_buf;
    float* g_buf = p;   p += big;
    ushort* xh = (ushort*)p; p += half;   // shared per-branch mix scratch
    ushort* xl = (ushort*)p; p += half;
    ushort* z_bf = xh;                    // z overlays xh (x dead post stage-1)
    const size_t WBIG = 524288;           // 1024x1024 bf16, float units
    ushort* rwTh = (ushort*)p; p += WBIG;  ushort* rwTl = (ushort*)p; p += WBIG;
    ushort* kwTh = (ushort*)p; p += WBIG;  ushort* kwTl = (ushort*)p; p += WBIG;
    ushort* vwTh = (ushort*)p; p += WBIG;  ushort* vwTl = (ushort*)p; p += WBIG;
    ushort* outTh = (ushort*)p; p += WBIG;              // plain (no lo)
    ushort* w1Th = (ushort*)p; p += 32768; ushort* w1Tl = (ushort*)p; p += 32768;
    ushort* a1Th = (ushort*)p; p += 32768; ushort* a1Tl = (ushort*)p; p += 32768;
    ushort* v1Th = (ushort*)p; p += 16384; ushort* v1Tl = (ushort*)p; p += 16384;
    ushort* g1Th = (ushort*)p; p += 65536;              // plain
    ushort* w2Th = (ushort*)p; p += 32768; ushort* w2Tl = (ushort*)p; p += 32768;
    ushort* a2Th = (ushort*)p; p += 32768; ushort* a2Tl = (ushort*)p; p += 32768;
    ushort* v2Th = (ushort*)p; p += 16384; ushort* v2Tl = (ushort*)p; p += 16384;
    ushort* g2Th = (ushort*)p; p += 65536;              // plain
    ushort* hwh = (ushort*)p; p += 131072; ushort* hwl = (ushort*)p; p += 131072;
    ushort* hah = (ushort*)p; p += 131072; ushort* hal = (ushort*)p; p += 131072;
    ushort* hvh = (ushort*)p; p += 65536;  ushort* hvl = (ushort*)p; p += 65536;
    ushort* hgh = (ushort*)p; p += 262144;              // plain
    float* rks_buf = p;        p += 65536;

    dim3 blk(256);
    dim3 t32x8(32, 8);

    // ---- weight transposes (split except g path / out_W)
    transpose_split<<<dim3(32, 32), t32x8, 0, stream>>>(rw_W, rwTh, rwTl, 1024, 1024);
    transpose_split<<<dim3(32, 32), t32x8, 0, stream>>>(kw_W, kwTh, kwTl, 1024, 1024);
    transpose_split<<<dim3(32, 32), t32x8, 0, stream>>>(vw_W, vwTh, vwTl, 1024, 1024);
    transpose_split<<<dim3(32, 32), t32x8, 0, stream>>>(out_W, outTh, nullptr, 1024, 1024);
    transpose_split<<<dim3(2, 32), t32x8, 0, stream>>>(w1, w1Th, w1Tl, 1024, 64);
    transpose_split<<<dim3(2, 32), t32x8, 0, stream>>>(a1, a1Th, a1Tl, 1024, 64);
    transpose_split<<<dim3(1, 32), t32x8, 0, stream>>>(v1, v1Th, v1Tl, 1024, 32);
    transpose_split<<<dim3(4, 32), t32x8, 0, stream>>>(g1, g1Th, nullptr, 1024, 128);
    transpose_split<<<dim3(32, 2), t32x8, 0, stream>>>(w2, w2Th, w2Tl, 64, 1024);
    transpose_split<<<dim3(32, 2), t32x8, 0, stream>>>(a2, a2Th, a2Tl, 64, 1024);
    transpose_split<<<dim3(32, 1), t32x8, 0, stream>>>(v2, v2Th, v2Tl, 32, 1024);
    transpose_split<<<dim3(32, 4), t32x8, 0, stream>>>(g2, g2Th, nullptr, 128, 1024);

    dim3 gBig(32, 8), gN1(32, 1);

    // ---- branch r
    mix_split<<<NT, blk, 0, stream>>>(cur, prev, rwkvag + 0 * DD, xh, xl);
    gemm_bf16s<<<gBig, blk, 0, stream>>>(xh, xl, rwTh, rwTl, nullptr, r_buf, nullptr, nullptr, 1024, 1024, 0);
    // ---- branch w (LoRA stage 1, tanh, split hidden)
    mix_split<<<NT, blk, 0, stream>>>(cur, prev, rwkvag + 1 * DD, xh, xl);
    gemm_bf16s<<<gN1, blk, 0, stream>>>(xh, xl, w1Th, w1Tl, nullptr, nullptr, hwh, hwl, 64, 1024, 1);
    // ---- branch k
    mix_split<<<NT, blk, 0, stream>>>(cur, prev, rwkvag + 2 * DD, xh, xl);
    gemm_bf16s<<<gBig, blk, 0, stream>>>(xh, xl, kwTh, kwTl, nullptr, k_buf, nullptr, nullptr, 1024, 1024, 0);
    // ---- branch v (big GEMM + v-gate LoRA stage 1)
    mix_split<<<NT, blk, 0, stream>>>(cur, prev, rwkvag + 3 * DD, xh, xl);
    gemm_bf16s<<<gBig, blk, 0, stream>>>(xh, xl, vwTh, vwTl, nullptr, v_buf, nullptr, nullptr, 1024, 1024, 0);
    gemm_bf16s<<<gN1, blk, 0, stream>>>(xh, xl, v1Th, v1Tl, nullptr, nullptr, hvh, hvl, 32, 1024, 0);
    // ---- branch a (LoRA stage 1)
    mix_split<<<NT, blk, 0, stream>>>(cur, prev, rwkvag + 4 * DD, xh, xl);
    gemm_bf16s<<<gN1, blk, 0, stream>>>(xh, xl, a1Th, a1Tl, nullptr, nullptr, hah, hal, 64, 1024, 0);
    // ---- branch g (plain bf16 path, sigmoid hidden)
    mix_split<<<NT, blk, 0, stream>>>(cur, prev, rwkvag + 5 * DD, xh, nullptr);
    gemm_bf16s<<<gN1, blk, 0, stream>>>(xh, nullptr, g1Th, nullptr, nullptr, nullptr, hgh, nullptr, 128, 1024, 2);

    // ---- LoRA stage 2
    gemm_bf16s<<<gBig, blk, 0, stream>>>(hwh, hwl, w2Th, w2Tl, w2_b, w_buf, nullptr, nullptr, 1024, 64, 0);
    gemm_bf16s<<<gBig, blk, 0, stream>>>(hah, hal, a2Th, a2Tl, a2_b, a_buf, nullptr, nullptr, 1024, 64, 2);
    gemm_bf16s<<<gBig, blk, 0, stream>>>(hvh, hvl, v2Th, v2Tl, v2_b, vg_buf, nullptr, nullptr, 1024, 32, 2);
    gemm_bf16s<<<gBig, blk, 0, stream>>>(hgh, nullptr, g2Th, nullptr, g2_b, g_buf, nullptr, nullptr, 1024, 128, 0);

    // ---- elementwise + scan + epilogue
    elemwise1<<<NT, blk, 0, stream>>>(r_buf, w_buf, k_buf, v_buf, kkn_buf, a_buf,
                                      vg_buf, vfirst, k_k, k_a, r_k, rks_buf);

    scan_kernel<<<dim3(64, 4), blk, 0, stream>>>(r_buf, w_buf, k_buf, kkn_buf, a_buf, v_buf,
                                                 os_buf, state_out);

    elemwise2<<<NT, blk, 0, stream>>>(os_buf, rks_buf, v_buf, g_buf, gn_s, gn_b, z_bf);

    // ---- y = z @ out_W (plain bf16)
    gemm_bf16s<<<gBig, blk, 0, stream>>>(z_bf, nullptr, outTh, nullptr, nullptr, y_out, nullptr, nullptr, 1024, 1024, 0);

    // ---- v_first passthrough
    hipMemcpyAsync(vf_out, vfirst, (size_t)NT * DD * sizeof(float),
                   hipMemcpyDeviceToDevice, stream);
}